// Round 7
// baseline (7927.803 us; speedup 1.0000x reference)
//
#include <hip/hip_runtime.h>

typedef unsigned short u16;
typedef __attribute__((ext_vector_type(8))) short short8;
typedef __attribute__((ext_vector_type(4))) float f32x4;

#define DEV __device__ __forceinline__

// B=192, T=64, ACT=16, EMB=1024, STOCH=32, DETER=600, HID=600
// out row stride 1392: [mean_po 0, std_po 32, stoch_po 64, deter 96,
//                       mean_pr 696, std_pr 728, stoch_pr 760, deter 792]
// xd row stride 1280: [x 0..599, deter 600..1199, zero pad 1200..1279]
#define XDS 1280
#define NBLK 192

DEV u16 f2bf(float f) {
  unsigned u = __float_as_uint(f);
  u = (u + 0x7FFFu + ((u >> 16) & 1u)) >> 16;
  return (u16)u;
}
DEV float bf2f(u16 h) { return __uint_as_float(((unsigned)h) << 16); }
DEV float sigf(float x) { return 1.f / (1.f + __expf(-x)); }
DEV float eluf(float x) { return x > 0.f ? x : __expf(x) - 1.f; }
DEV f32x4 MF(short8 a, short8 b, f32x4 c) {
  return __builtin_amdgcn_mfma_f32_16x16x32_bf16(a, b, c, 0, 0, 0);
}

// ---- agent-coherent (sc1, MALL-served) helpers: bypass L1/L2 so no fence /
// ---- L2 invalidate is needed; read-only weights stay warm in L2. ----
DEV unsigned long long ald64(const void* p) {
  return __hip_atomic_load((const unsigned long long*)p, __ATOMIC_RELAXED,
                           __HIP_MEMORY_SCOPE_AGENT);
}
DEV short8 ald16B(const u16* p) {
  union { unsigned long long u[2]; short8 v; } x;
  x.u[0] = ald64(p);
  x.u[1] = ald64(p + 4);
  return x.v;
}
DEV void ast32(void* p, unsigned v) {
  __hip_atomic_store((unsigned*)p, v, __ATOMIC_RELAXED, __HIP_MEMORY_SCOPE_AGENT);
}
DEV void astf(float* p, float v) { ast32(p, __float_as_uint(v)); }
DEV unsigned ald32(const unsigned* p) {
  return __hip_atomic_load(p, __ATOMIC_RELAXED, __HIP_MEMORY_SCOPE_AGENT);
}

// ---- flag-vector grid barrier: one sc1 store per block (own 4B slot, no RMW);
// ---- 64 lanes poll ALL 192 flags (3 each, coalesced), s_sleep backoff.
// ---- __syncthreads drains vmcnt(0) per wave => all sc1 data stores are
// ---- MALL-visible before the flag store issues. seq monotonic, no reset.
DEV void gbar(unsigned* flags, unsigned seq) {
  __syncthreads();
  const int tid = threadIdx.x;
  if (tid == 0) ast32(&flags[blockIdx.x], seq);
  if (tid < 64) {
    for (;;) {
      unsigned v0 = ald32(&flags[tid]);
      unsigned v1 = ald32(&flags[tid + 64]);
      unsigned v2 = ald32(&flags[tid + 128]);
      unsigned mn = min(v0, min(v1, v2));
      if (__all((int)(mn >= seq))) break;
      __builtin_amdgcn_s_sleep(1);
    }
  }
  __syncthreads();
}

// ---------------- f32 -> bf16 with zero row padding (k-major) ----------------
__global__ __launch_bounds__(256) void conv_pad(const float* __restrict__ src,
                                                u16* __restrict__ dst,
                                                int K, int N, int Kpad, int srcRowOff) {
  size_t total = (size_t)Kpad * N;
  for (size_t idx = (size_t)blockIdx.x * 256 + threadIdx.x; idx < total;
       idx += (size_t)gridDim.x * 256) {
    int k = (int)(idx / (size_t)N);
    int n = (int)(idx % (size_t)N);
    dst[idx] = (k < K) ? f2bf(src[(size_t)(k + srcRowOff) * N + n]) : (u16)0;
  }
}

// ---------------- f32 [K0][N0] -> bf16 transposed [Npad][Kpad] ----------------
__global__ __launch_bounds__(256) void conv_T(const float* __restrict__ src,
                                              u16* __restrict__ dst,
                                              int K0, int N0, int Kpad, int Npad) {
  size_t total = (size_t)Npad * Kpad;
  for (size_t idx = (size_t)blockIdx.x * 256 + threadIdx.x; idx < total;
       idx += (size_t)gridDim.x * 256) {
    int n = (int)(idx / (size_t)Kpad);
    int k = (int)(idx % (size_t)Kpad);
    dst[idx] = (k < K0 && n < N0) ? f2bf(src[(size_t)k * N0 + n]) : (u16)0;
  }
}

// ---------------- MFMA 64x64 tile core (LDS-staged, for setup/tail GEMMs) ----
DEV void mfma_tile(const u16 (*As)[72], const u16 (*Bs)[72], int wm, int wn,
                   int lane, f32x4 acc[2][2]) {
#pragma unroll
  for (int s = 0; s < 2; ++s) {
    const int ko = s * 32 + ((lane >> 4) << 3);
    short8 a0 = *reinterpret_cast<const short8*>(&As[wm + (lane & 15)][ko]);
    short8 a1 = *reinterpret_cast<const short8*>(&As[wm + 16 + (lane & 15)][ko]);
    short8 b0 = *reinterpret_cast<const short8*>(&Bs[wn + (lane & 15)][ko]);
    short8 b1 = *reinterpret_cast<const short8*>(&Bs[wn + 16 + (lane & 15)][ko]);
    acc[0][0] = MF(a0, b0, acc[0][0]);
    acc[0][1] = MF(a0, b1, acc[0][1]);
    acc[1][0] = MF(a1, b0, acc[1][0]);
    acc[1][1] = MF(a1, b1, acc[1][1]);
  }
}

// ---------------- generic 64x64-tiled bf16 GEMM (setup/tail) ----------------
// EPI: 2 = +bias, elu, bf16 out ; 4 = +bias, bf16 out, epre-permuted store
template <int EPI>
__global__ __launch_bounds__(256) void gemm64(
    const u16* __restrict__ A, int lda, const u16* __restrict__ W, int ldw,
    const float* __restrict__ bias, void* __restrict__ Cv, int ldc,
    int Nstore, int N, int K) {
  __shared__ u16 As[64][72];
  __shared__ u16 Bs[64][72];
  const int tid = threadIdx.x, lane = tid & 63, wave = tid >> 6;
  const int wm = (wave & 1) * 32, wn = (wave >> 1) * 32;
  const int bn0 = blockIdx.x * 64, bm0 = blockIdx.y * 64;
  const int am = tid >> 2, ak0 = (tid & 3) * 16;
  const int bk = tid >> 3, bn = (tid & 7) * 8;

  f32x4 acc[2][2] = {};
  for (int k0 = 0; k0 < K; k0 += 64) {
    __syncthreads();
    {
      const u16* src = A + (size_t)(bm0 + am) * lda + k0 + ak0;
      *reinterpret_cast<short8*>(&As[am][ak0]) = *reinterpret_cast<const short8*>(src);
      *reinterpret_cast<short8*>(&As[am][ak0 + 8]) = *reinterpret_cast<const short8*>(src + 8);
    }
    {
      int gn = bn0 + bn;
#pragma unroll
      for (int h = 0; h < 2; ++h) {
        int kk = k0 + bk + h * 32;
        short8 v;
        if (gn + 7 < N) {
          v = *reinterpret_cast<const short8*>(W + (size_t)kk * ldw + gn);
        } else {
          for (int j = 0; j < 8; ++j)
            v[j] = (gn + j < N) ? (short)W[(size_t)kk * ldw + gn + j] : (short)0;
        }
#pragma unroll
        for (int j = 0; j < 8; ++j) Bs[bn + j][bk + h * 32] = (u16)v[j];
      }
    }
    __syncthreads();
    mfma_tile(As, Bs, wm, wn, lane, acc);
  }

#pragma unroll
  for (int r = 0; r < 2; ++r)
#pragma unroll
    for (int c = 0; c < 2; ++c)
#pragma unroll
      for (int i = 0; i < 4; ++i) {
        int grow = bm0 + wm + r * 16 + ((lane >> 4) << 2) + i;
        int gcol = bn0 + wn + c * 16 + (lane & 15);
        if (gcol >= Nstore) continue;
        bool ok = gcol < N;
        float v = acc[r][c][i] + (ok ? bias[gcol] : 0.f);
        if (EPI == 2) {
          v = eluf(v);
          ((u16*)Cv)[(size_t)grow * ldc + gcol] = ok ? f2bf(v) : (u16)0;
        } else {  // EPI 4: epre[t][b][600] layout
          size_t row2 = (size_t)(grow & 63) * 192 + (size_t)(grow >> 6);
          ((u16*)Cv)[row2 * 600 + gcol] = f2bf(v);
        }
      }
}

// ------- init: x(t=0)=elu(action part), deter=0, pads=0, flags=0 ----------
__global__ __launch_bounds__(256) void k_init(const float* __restrict__ action,
                                              const float* __restrict__ img1w,
                                              const float* __restrict__ img1b,
                                              u16* __restrict__ xd,
                                              unsigned* __restrict__ flags) {
  __shared__ float act[16];
  int b = blockIdx.x, tid = threadIdx.x;
  if (tid == 0) flags[b] = 0;  // kernel-end flush makes this visible
  if (tid < 16) act[tid] = action[(size_t)b * 64 * 16 + tid];  // t = 0
  __syncthreads();
  for (int h = tid; h < 600; h += 256) {
    float s = img1b[h];
#pragma unroll
    for (int a = 0; a < 16; ++a) s += act[a] * img1w[(size_t)(32 + a) * 600 + h];
    xd[(size_t)b * XDS + h] = f2bf(eluf(s));
  }
  for (int j = tid; j < 680; j += 256) xd[(size_t)b * XDS + 600 + j] = 0;
}

// ---------------- batched prior head (tail; N=64 GEMM + dist outputs) --------
__global__ __launch_bounds__(256) void head_prior(
    const u16* __restrict__ A, const u16* __restrict__ W,
    const float* __restrict__ bias64, const float* __restrict__ noise,
    float* __restrict__ out) {
  __shared__ u16 As[64][72];
  __shared__ u16 Bs[64][72];
  __shared__ float sl[64][68];
  const int tid = threadIdx.x, lane = tid & 63, wave = tid >> 6;
  const int wm = (wave & 1) * 32, wn = (wave >> 1) * 32;
  const int bm0 = blockIdx.x * 64;
  const int am = tid >> 2, ak0 = (tid & 3) * 16;
  const int bk = tid >> 3, bn = (tid & 7) * 8;

  f32x4 acc[2][2] = {};
  for (int k0 = 0; k0 < 640; k0 += 64) {
    __syncthreads();
    {
      const u16* src = A + (size_t)(bm0 + am) * 640 + k0 + ak0;
      *reinterpret_cast<short8*>(&As[am][ak0]) = *reinterpret_cast<const short8*>(src);
      *reinterpret_cast<short8*>(&As[am][ak0 + 8]) = *reinterpret_cast<const short8*>(src + 8);
    }
#pragma unroll
    for (int h = 0; h < 2; ++h) {
      int kk = k0 + bk + h * 32;
      short8 v = *reinterpret_cast<const short8*>(W + (size_t)kk * 64 + bn);
#pragma unroll
      for (int j = 0; j < 8; ++j) Bs[bn + j][bk + h * 32] = (u16)v[j];
    }
    __syncthreads();
    mfma_tile(As, Bs, wm, wn, lane, acc);
  }
#pragma unroll
  for (int r = 0; r < 2; ++r)
#pragma unroll
    for (int c = 0; c < 2; ++c)
#pragma unroll
      for (int i = 0; i < 4; ++i) {
        int col = wn + c * 16 + (lane & 15);
        sl[wm + r * 16 + ((lane >> 4) << 2) + i][col] = acc[r][c][i] + bias64[col];
      }
  __syncthreads();
  for (int task = tid; task < 64 * 32; task += 256) {
    int r = task >> 5, j = task & 31;
    size_t orow = (size_t)(bm0 + r);
    size_t base = orow * 1392 + 696;
    float mean = sl[r][j];
    float sd = 2.f * sigf(0.5f * sl[r][32 + j]) + 0.1f;
    float st = mean + sd * noise[orow * 32 + j];
    out[base + j] = mean;
    out[base + 32 + j] = sd;
    out[base + 64 + j] = st;
  }
}

// ---------------- the persistent scan kernel (plain launch + own barrier) ----
struct ScanArgs {
  u16* xd;            // [192][XDS] carry (sc1)
  float* parts;       // [192][1800] (sc1)
  const u16* gruwT;   // [1800][1216] (cached)
  const float* grub;
  const float* lns;
  const float* lnb;
  u16* dall;          // [12288][640] (plain; read after kernel end)
  float* out;
  const u16* o1wT;    // [640][640]
  const u16* epre;    // [64][192][600] (t-major)
  const u16* o2wT;    // [64][640]
  const float* obs2b;
  const float* npo;
  const u16* w1pT;    // [640][64]
  const float* img1b;
  const float* action;
  unsigned* flags;
};

__global__ __launch_bounds__(256, 1) void scan64(ScanArgs A) {
  const int bid = blockIdx.x, tid = threadIdx.x;
  const int lane = tid & 63, wave = tid >> 6;
  const int l15 = lane & 15;
  const int koff = (lane >> 4) << 3;   // k-octet offset within 32-k slab
  const int crow = (lane >> 4) << 2;   // C-row base within 16

  __shared__ float pl[1800];
  __shared__ float red[256];
  __shared__ float dsh[600];   // per-block deter carry (block b <-> batch row b)
  __shared__ float sl[16][68];
  __shared__ u16 xa[16][72];
  __shared__ u16 dl[16][648];  // CD: staged deter rows
  __shared__ u16 hl[16][648];  // CD: obs1 output h

  for (int j = tid; j < 600; j += 256) dsh[j] = 0.f;
  unsigned seq = 0;

  for (int t = 0; t < 64; ++t) {
    // ======== Phase A: parts[192][1800] = xd @ gruw  (45 blocks, 64x128) ====
    if (bid < 45) {
      const int tm = bid / 15, tn = bid - tm * 15;
      const int bm0 = tm * 64, bn0 = tn * 128;
      const int wm = (wave & 1) * 32;
      const int wn2 = (wave >> 1) * 64;
      const u16* a0p = A.xd + (size_t)(bm0 + wm + l15) * XDS + koff;
      const u16* a1p = a0p + (size_t)16 * XDS;
      int cc[4];
      const u16* bp[4];
#pragma unroll
      for (int j = 0; j < 4; ++j) {
        cc[j] = bn0 + wn2 + j * 16 + l15;
        bp[j] = A.gruwT + (size_t)(cc[j] < 1800 ? cc[j] : 0) * 1216 + koff;
      }
      f32x4 acc[2][4] = {};
#pragma unroll 2
      for (int kk = 0; kk < 1216; kk += 32) {
        short8 a0 = ald16B(a0p + kk);
        short8 a1 = ald16B(a1p + kk);
#pragma unroll
        for (int j = 0; j < 4; ++j) {
          short8 b = *reinterpret_cast<const short8*>(bp[j] + kk);
          acc[0][j] = MF(a0, b, acc[0][j]);
          acc[1][j] = MF(a1, b, acc[1][j]);
        }
      }
#pragma unroll
      for (int i = 0; i < 4; ++i) {
        float* p0 = A.parts + (size_t)(bm0 + wm + crow + i) * 1800;
        float* p1 = p0 + 16 * 1800;
#pragma unroll
        for (int j = 0; j < 4; ++j) {
          if (cc[j] < 1800) {
            astf(&p0[cc[j]], acc[0][j][i]);
            astf(&p1[cc[j]], acc[1][j][i]);
          }
        }
      }
    }
    gbar(A.flags, ++seq);

    // ======== Phase B: LN + GRU gates, one batch row per block ========
    {
      const int b = bid;
      float s = 0.f;
#pragma unroll
      for (int it = 0; it < 4; ++it) {
        int i2 = it * 256 + tid;
        if (i2 < 900) {
          unsigned long long u = ald64(A.parts + (size_t)b * 1800 + i2 * 2);
          float vx = __uint_as_float((unsigned)u) + A.grub[i2 * 2];
          float vy = __uint_as_float((unsigned)(u >> 32)) + A.grub[i2 * 2 + 1];
          pl[i2 * 2] = vx;
          pl[i2 * 2 + 1] = vy;
          s += vx + vy;
        }
      }
      red[tid] = s;
      __syncthreads();
      for (int o = 128; o > 0; o >>= 1) {
        if (tid < o) red[tid] += red[tid + o];
        __syncthreads();
      }
      float m = red[0] * (1.f / 1800.f);
      __syncthreads();
      float q = 0.f;
#pragma unroll
      for (int it = 0; it < 8; ++it) {
        int i = it * 256 + tid;
        if (i < 1800) {
          float d = pl[i] - m;
          q += d * d;
        }
      }
      red[tid] = q;
      __syncthreads();
      for (int o = 128; o > 0; o >>= 1) {
        if (tid < o) red[tid] += red[tid + o];
        __syncthreads();
      }
      float rstd = rsqrtf(red[0] * (1.f / 1800.f) + 1e-5f);
      size_t orow = (size_t)b * 64 + t;
#pragma unroll
      for (int it = 0; it < 3; ++it) {
        int j = it * 256 + tid;
        if (j < 600) {
          float p0 = (pl[j] - m) * rstd * A.lns[j] + A.lnb[j];
          float p1 = (pl[600 + j] - m) * rstd * A.lns[600 + j] + A.lnb[600 + j];
          float p2 = (pl[1200 + j] - m) * rstd * A.lns[1200 + j] + A.lnb[1200 + j];
          float r = sigf(p0);
          float cd = tanhf(r * p1);
          float u = sigf(p2 - 1.f);
          float dn = u * cd + (1.f - u) * dsh[j];
          dsh[j] = dn;
          A.out[orow * 1392 + 96 + j] = dn;
          A.out[orow * 1392 + 792 + j] = dn;
        }
      }
      __syncthreads();
      // pack deter to bf16 pairs: sc1 into xd, plain into dall
      for (int it = 0; it < 2; ++it) {
        int idx = it * 256 + tid;
        if (idx < 300) {
          int j = idx * 2;
          unsigned pk = (unsigned)f2bf(dsh[j]) | ((unsigned)f2bf(dsh[j + 1]) << 16);
          ast32(A.xd + (size_t)b * XDS + 600 + j, pk);
          *reinterpret_cast<unsigned*>(A.dall + orow * 640 + j) = pk;
        }
      }
      if (tid < 20) *reinterpret_cast<unsigned*>(A.dall + orow * 640 + 600 + tid * 2) = 0;
    }
    gbar(A.flags, ++seq);

    // ======== Phase CD: obs1 + obs2 + head + next x (12 blocks, 16 rows) ====
    if (bid < 12) {
      const int r0 = bid * 16;
      // stage deter (16 rows x 640, rows 600..1239 of xd incl. zero pad)
      for (int ch = tid; ch < 1280; ch += 256) {
        int r = ch / 80, k8 = (ch - r * 80) * 8;
        *reinterpret_cast<short8*>(&dl[r][k8]) =
            ald16B(A.xd + (size_t)(r0 + r) * XDS + 600 + k8);
      }
      __syncthreads();
      // obs1: hl = elu(deter @ obs1_w[:600] + epre), cols padded to 640
      {
        const int n0w = wave * 160;
#pragma unroll
        for (int ct = 0; ct < 10; ++ct) {
          const int c = n0w + ct * 16 + l15;
          const u16* bp = A.o1wT + (size_t)c * 640 + koff;
          f32x4 acc{};
#pragma unroll 5
          for (int kk = 0; kk < 640; kk += 32)
            acc = MF(*reinterpret_cast<const short8*>(&dl[l15][koff + kk]),
                     *reinterpret_cast<const short8*>(bp + kk), acc);
#pragma unroll
          for (int i = 0; i < 4; ++i) {
            int r = crow + i;
            u16 h = 0;
            if (c < 600)
              h = f2bf(eluf(acc[i] +
                            bf2f(A.epre[((size_t)t * 192 + r0 + r) * 600 + c])));
            hl[r][c] = h;
          }
        }
      }
      __syncthreads();
      // obs2: sl[16][64] = hl @ obs2_w + obs2_b
      {
        const int n0 = wave * 16;
        const u16* bp = A.o2wT + (size_t)(n0 + l15) * 640 + koff;
        f32x4 acc{};
#pragma unroll 5
        for (int kk = 0; kk < 640; kk += 32)
          acc = MF(*reinterpret_cast<const short8*>(&hl[l15][koff + kk]),
                   *reinterpret_cast<const short8*>(bp + kk), acc);
#pragma unroll
        for (int i = 0; i < 4; ++i)
          sl[crow + i][n0 + l15] = acc[i] + A.obs2b[n0 + l15];
      }
      __syncthreads();
      // head outputs + stoch + xa
      for (int task = tid; task < 512; task += 256) {
        int r = task >> 5, j = task & 31;
        size_t orow = (size_t)(r0 + r) * 64 + t;
        float mean = sl[r][j];
        float sd = 2.f * sigf(0.5f * sl[r][32 + j]) + 0.1f;
        float st = mean + sd * A.npo[orow * 32 + j];
        float* ob = A.out + orow * 1392;
        ob[j] = mean;
        ob[32 + j] = sd;
        ob[64 + j] = st;
        xa[r][j] = f2bf(st);
      }
      {
        int r = tid >> 4, a2 = tid & 15;
        xa[r][32 + a2] =
            (t < 63) ? f2bf(A.action[((size_t)(r0 + r) * 64 + t + 1) * 16 + a2]) : (u16)0;
        xa[r][48 + a2] = 0;
      }
      __syncthreads();
      // next x = elu([stoch, action_{t+1}] @ img1_w + img1_b) -> xd (sc1)
      if (t < 63) {
        for (int g = wave; g < 38; g += 4) {
          const u16* bp = A.w1pT + (size_t)(g * 16 + l15) * 64 + koff;
          f32x4 ax{};
          ax = MF(*reinterpret_cast<const short8*>(&xa[l15][koff]),
                  *reinterpret_cast<const short8*>(bp), ax);
          ax = MF(*reinterpret_cast<const short8*>(&xa[l15][32 + koff]),
                  *reinterpret_cast<const short8*>(bp + 32), ax);
          int c = g * 16 + l15;
          if (c < 600) {
            float bi = A.img1b[c];
#pragma unroll
            for (int i = 0; i < 4; ++i) {
              unsigned hv = f2bf(eluf(ax[i] + bi));
              unsigned ov = (unsigned)__shfl_xor((int)hv, 1);
              if (!(l15 & 1))
                ast32(A.xd + (size_t)(r0 + crow + i) * XDS + c, hv | (ov << 16));
            }
          }
        }
      }
      __syncthreads();  // protect sl/xa/dl/hl before next iteration
    }
    gbar(A.flags, ++seq);
  }
}

// ---------------- launch ----------------
extern "C" void kernel_launch(void* const* d_in, const int* in_sizes, int n_in,
                              void* d_out, int out_size, void* d_ws, size_t ws_size,
                              hipStream_t stream) {
  (void)in_sizes; (void)n_in; (void)out_size; (void)ws_size;
  const float* action = (const float*)d_in[0];
  const float* embed = (const float*)d_in[1];
  const float* npr = (const float*)d_in[2];
  const float* npo = (const float*)d_in[3];
  const float* img1w = (const float*)d_in[4];
  const float* img1b = (const float*)d_in[5];
  const float* gruw = (const float*)d_in[6];
  const float* grub = (const float*)d_in[7];
  const float* lns = (const float*)d_in[8];
  const float* lnb = (const float*)d_in[9];
  const float* img2w = (const float*)d_in[10];
  const float* img2b = (const float*)d_in[11];
  const float* img3w = (const float*)d_in[12];
  const float* img3b = (const float*)d_in[13];
  const float* obs1w = (const float*)d_in[14];
  const float* obs1b = (const float*)d_in[15];
  const float* obs2w = (const float*)d_in[16];
  const float* obs2b = (const float*)d_in[17];
  float* out = (float*)d_out;
  char* ws = (char*)d_ws;

  size_t off = 0;
  auto alloc = [&](size_t bytes) {
    size_t o = off;
    off += (bytes + 255) & ~(size_t)255;
    return o;
  };
  size_t o_bar = alloc(1024);
  size_t o_embed = alloc(12288ull * 1024 * 2);  // reused as dall (12288x640)
  size_t o_epre = alloc(12288ull * 600 * 2);    // reused (with o_wemb) as h_img
  size_t o_wemb = alloc(1024ull * 600 * 2);
  size_t o_gruwT = alloc(1800ull * 1216 * 2);
  size_t o_o1wT = alloc(640ull * 640 * 2);
  size_t o_o2wT = alloc(64ull * 640 * 2);
  size_t o_w1pT = alloc(640ull * 64 * 2);
  size_t o_i2w = alloc(640ull * 600 * 2);
  size_t o_i3w = alloc(640ull * 64 * 2);
  size_t o_xd = alloc(192ull * XDS * 2);
  size_t o_parts = alloc(192ull * 1800 * 4);

  unsigned* flags = (unsigned*)(ws + o_bar);
  u16* embed_bf = (u16*)(ws + o_embed);
  u16* dall = (u16*)(ws + o_embed);
  u16* epre = (u16*)(ws + o_epre);
  u16* himg = (u16*)(ws + o_epre);
  u16* wemb = (u16*)(ws + o_wemb);
  u16* gruwT = (u16*)(ws + o_gruwT);
  u16* o1wT = (u16*)(ws + o_o1wT);
  u16* o2wT = (u16*)(ws + o_o2wT);
  u16* w1pT = (u16*)(ws + o_w1pT);
  u16* i2wb = (u16*)(ws + o_i2w);
  u16* i3wb = (u16*)(ws + o_i3w);
  u16* xd = (u16*)(ws + o_xd);
  float* parts = (float*)(ws + o_parts);

  auto cgr = [](size_t total) {
    size_t g = (total + 255) / 256;
    return (unsigned)(g > 4096 ? 4096 : g);
  };

  // setup conversions
  conv_pad<<<cgr(12288ull * 1024), 256, 0, stream>>>(embed, embed_bf, 12288, 1024, 12288, 0);
  conv_pad<<<cgr(1024ull * 600), 256, 0, stream>>>(obs1w, wemb, 1024, 600, 1024, 600);
  conv_pad<<<cgr(640ull * 600), 256, 0, stream>>>(img2w, i2wb, 600, 600, 640, 0);
  conv_pad<<<cgr(640ull * 64), 256, 0, stream>>>(img3w, i3wb, 600, 64, 640, 0);
  conv_T<<<cgr(1800ull * 1216), 256, 0, stream>>>(gruw, gruwT, 1200, 1800, 1216, 1800);
  conv_T<<<cgr(640ull * 640), 256, 0, stream>>>(obs1w, o1wT, 600, 600, 640, 640);
  conv_T<<<cgr(64ull * 640), 256, 0, stream>>>(obs2w, o2wT, 600, 64, 640, 64);
  conv_T<<<cgr(640ull * 64), 256, 0, stream>>>(img1w, w1pT, 48, 600, 64, 640);

  k_init<<<192, 256, 0, stream>>>(action, img1w, img1b, xd, flags);

  // epre[t][b][600] = embed @ obs1_w[600:,:] + obs1_b   (bf16, t-major)
  gemm64<4><<<dim3(10, 192), 256, 0, stream>>>(embed_bf, 1024, wemb, 600, obs1b,
                                               epre, 600, 600, 600, 1024);

  // the whole 64-step scan in one plain-launch kernel with a flag-vector barrier
  ScanArgs sa;
  sa.xd = xd; sa.parts = parts;
  sa.gruwT = gruwT; sa.grub = grub; sa.lns = lns; sa.lnb = lnb;
  sa.dall = dall; sa.out = out;
  sa.o1wT = o1wT; sa.epre = epre;
  sa.o2wT = o2wT; sa.obs2b = obs2b; sa.npo = npo;
  sa.w1pT = w1pT; sa.img1b = img1b; sa.action = action;
  sa.flags = flags;
  scan64<<<NBLK, 256, 0, stream>>>(sa);

  // batched prior: h_img = elu(deter_all @ img2_w + img2_b), then img3 head
  gemm64<2><<<dim3(10, 192), 256, 0, stream>>>(dall, 640, i2wb, 600, img2b,
                                               himg, 640, 640, 600, 640);
  head_prior<<<192, 256, 0, stream>>>(himg, i3wb, img3b, npr, out);
}

// Round 8
// 5269.674 us; speedup vs baseline: 1.5044x; 1.5044x over previous
//
#include <hip/hip_runtime.h>

typedef unsigned short u16;
typedef __attribute__((ext_vector_type(8))) short short8;
typedef __attribute__((ext_vector_type(4))) float f32x4;

#define DEV __device__ __forceinline__

// B=192, T=64, ACT=16, EMB=1024, STOCH=32, DETER=600, HID=600
// out row stride 1392: [mean_po 0, std_po 32, stoch_po 64, deter 96,
//                       mean_pr 696, std_pr 728, stoch_pr 760, deter 792]
// xd row stride 1280: [x 0..599, deter 600..1199, zero pad 1200..1279]
#define XDS 1280
#define NBLK 102   // 90 A-blocks + 12 BCD-blocks

DEV u16 f2bf(float f) {
  unsigned u = __float_as_uint(f);
  u = (u + 0x7FFFu + ((u >> 16) & 1u)) >> 16;
  return (u16)u;
}
DEV float bf2f(u16 h) { return __uint_as_float(((unsigned)h) << 16); }
DEV float sigf(float x) { return 1.f / (1.f + __expf(-x)); }
DEV float eluf(float x) { return x > 0.f ? x : __expf(x) - 1.f; }
DEV f32x4 MF(short8 a, short8 b, f32x4 c) {
  return __builtin_amdgcn_mfma_f32_16x16x32_bf16(a, b, c, 0, 0, 0);
}

// ---- agent-coherent (sc1, MALL-served) helpers: bypass L1/L2 so no fence /
// ---- L2 invalidate is needed; read-only weights stay warm in L2. ----
DEV unsigned long long ald64(const void* p) {
  return __hip_atomic_load((const unsigned long long*)p, __ATOMIC_RELAXED,
                           __HIP_MEMORY_SCOPE_AGENT);
}
DEV short8 ald16B(const u16* p) {
  union { unsigned long long u[2]; short8 v; } x;
  x.u[0] = ald64(p);
  x.u[1] = ald64(p + 4);
  return x.v;
}
DEV void ast32(void* p, unsigned v) {
  __hip_atomic_store((unsigned*)p, v, __ATOMIC_RELAXED, __HIP_MEMORY_SCOPE_AGENT);
}
DEV void astf(float* p, float v) { ast32(p, __float_as_uint(v)); }
DEV unsigned ald32(const unsigned* p) {
  return __hip_atomic_load(p, __ATOMIC_RELAXED, __HIP_MEMORY_SCOPE_AGENT);
}

// ---------------- f32 -> bf16 with zero row padding (k-major) ----------------
__global__ __launch_bounds__(256) void conv_pad(const float* __restrict__ src,
                                                u16* __restrict__ dst,
                                                int K, int N, int Kpad, int srcRowOff) {
  size_t total = (size_t)Kpad * N;
  for (size_t idx = (size_t)blockIdx.x * 256 + threadIdx.x; idx < total;
       idx += (size_t)gridDim.x * 256) {
    int k = (int)(idx / (size_t)N);
    int n = (int)(idx % (size_t)N);
    dst[idx] = (k < K) ? f2bf(src[(size_t)(k + srcRowOff) * N + n]) : (u16)0;
  }
}

// ---------------- f32 [K0][N0] -> bf16 transposed [Npad][Kpad] ----------------
__global__ __launch_bounds__(256) void conv_T(const float* __restrict__ src,
                                              u16* __restrict__ dst,
                                              int K0, int N0, int Kpad, int Npad) {
  size_t total = (size_t)Npad * Kpad;
  for (size_t idx = (size_t)blockIdx.x * 256 + threadIdx.x; idx < total;
       idx += (size_t)gridDim.x * 256) {
    int n = (int)(idx / (size_t)Kpad);
    int k = (int)(idx % (size_t)Kpad);
    dst[idx] = (k < K0 && n < N0) ? f2bf(src[(size_t)k * N0 + n]) : (u16)0;
  }
}

// ---------------- MFMA 64x64 tile core (LDS-staged, for setup/tail GEMMs) ----
DEV void mfma_tile(const u16 (*As)[72], const u16 (*Bs)[72], int wm, int wn,
                   int lane, f32x4 acc[2][2]) {
#pragma unroll
  for (int s = 0; s < 2; ++s) {
    const int ko = s * 32 + ((lane >> 4) << 3);
    short8 a0 = *reinterpret_cast<const short8*>(&As[wm + (lane & 15)][ko]);
    short8 a1 = *reinterpret_cast<const short8*>(&As[wm + 16 + (lane & 15)][ko]);
    short8 b0 = *reinterpret_cast<const short8*>(&Bs[wn + (lane & 15)][ko]);
    short8 b1 = *reinterpret_cast<const short8*>(&Bs[wn + 16 + (lane & 15)][ko]);
    acc[0][0] = MF(a0, b0, acc[0][0]);
    acc[0][1] = MF(a0, b1, acc[0][1]);
    acc[1][0] = MF(a1, b0, acc[1][0]);
    acc[1][1] = MF(a1, b1, acc[1][1]);
  }
}

// ---------------- generic 64x64-tiled bf16 GEMM (setup/tail) ----------------
// EPI: 2 = +bias, elu, bf16 out ; 4 = +bias, bf16 out, epre-permuted store
template <int EPI>
__global__ __launch_bounds__(256) void gemm64(
    const u16* __restrict__ A, int lda, const u16* __restrict__ W, int ldw,
    const float* __restrict__ bias, void* __restrict__ Cv, int ldc,
    int Nstore, int N, int K) {
  __shared__ u16 As[64][72];
  __shared__ u16 Bs[64][72];
  const int tid = threadIdx.x, lane = tid & 63, wave = tid >> 6;
  const int wm = (wave & 1) * 32, wn = (wave >> 1) * 32;
  const int bn0 = blockIdx.x * 64, bm0 = blockIdx.y * 64;
  const int am = tid >> 2, ak0 = (tid & 3) * 16;
  const int bk = tid >> 3, bn = (tid & 7) * 8;

  f32x4 acc[2][2] = {};
  for (int k0 = 0; k0 < K; k0 += 64) {
    __syncthreads();
    {
      const u16* src = A + (size_t)(bm0 + am) * lda + k0 + ak0;
      *reinterpret_cast<short8*>(&As[am][ak0]) = *reinterpret_cast<const short8*>(src);
      *reinterpret_cast<short8*>(&As[am][ak0 + 8]) = *reinterpret_cast<const short8*>(src + 8);
    }
    {
      int gn = bn0 + bn;
#pragma unroll
      for (int h = 0; h < 2; ++h) {
        int kk = k0 + bk + h * 32;
        short8 v;
        if (gn + 7 < N) {
          v = *reinterpret_cast<const short8*>(W + (size_t)kk * ldw + gn);
        } else {
          for (int j = 0; j < 8; ++j)
            v[j] = (gn + j < N) ? (short)W[(size_t)kk * ldw + gn + j] : (short)0;
        }
#pragma unroll
        for (int j = 0; j < 8; ++j) Bs[bn + j][bk + h * 32] = (u16)v[j];
      }
    }
    __syncthreads();
    mfma_tile(As, Bs, wm, wn, lane, acc);
  }

#pragma unroll
  for (int r = 0; r < 2; ++r)
#pragma unroll
    for (int c = 0; c < 2; ++c)
#pragma unroll
      for (int i = 0; i < 4; ++i) {
        int grow = bm0 + wm + r * 16 + ((lane >> 4) << 2) + i;
        int gcol = bn0 + wn + c * 16 + (lane & 15);
        if (gcol >= Nstore) continue;
        bool ok = gcol < N;
        float v = acc[r][c][i] + (ok ? bias[gcol] : 0.f);
        if (EPI == 2) {
          v = eluf(v);
          ((u16*)Cv)[(size_t)grow * ldc + gcol] = ok ? f2bf(v) : (u16)0;
        } else {  // EPI 4: epre[t][b][600] layout
          size_t row2 = (size_t)(grow & 63) * 192 + (size_t)(grow >> 6);
          ((u16*)Cv)[row2 * 600 + gcol] = f2bf(v);
        }
      }
}

// ------- init: x(t=0)=elu(action part), deter=0, pads=0, flags=0 ----------
__global__ __launch_bounds__(256) void k_init(const float* __restrict__ action,
                                              const float* __restrict__ img1w,
                                              const float* __restrict__ img1b,
                                              u16* __restrict__ xd,
                                              unsigned* __restrict__ flags) {
  __shared__ float act[16];
  int b = blockIdx.x, tid = threadIdx.x;
  if (b == 0 && tid < 128) flags[tid] = 0;  // kernel-end flush makes this visible
  if (tid < 16) act[tid] = action[(size_t)b * 64 * 16 + tid];  // t = 0
  __syncthreads();
  for (int h = tid; h < 600; h += 256) {
    float s = img1b[h];
#pragma unroll
    for (int a = 0; a < 16; ++a) s += act[a] * img1w[(size_t)(32 + a) * 600 + h];
    xd[(size_t)b * XDS + h] = f2bf(eluf(s));
  }
  for (int j = tid; j < 680; j += 256) xd[(size_t)b * XDS + 600 + j] = 0;
}

// ---------------- batched prior head (tail; N=64 GEMM + dist outputs) --------
__global__ __launch_bounds__(256) void head_prior(
    const u16* __restrict__ A, const u16* __restrict__ W,
    const float* __restrict__ bias64, const float* __restrict__ noise,
    float* __restrict__ out) {
  __shared__ u16 As[64][72];
  __shared__ u16 Bs[64][72];
  __shared__ float sl[64][68];
  const int tid = threadIdx.x, lane = tid & 63, wave = tid >> 6;
  const int wm = (wave & 1) * 32, wn = (wave >> 1) * 32;
  const int bm0 = blockIdx.x * 64;
  const int am = tid >> 2, ak0 = (tid & 3) * 16;
  const int bk = tid >> 3, bn = (tid & 7) * 8;

  f32x4 acc[2][2] = {};
  for (int k0 = 0; k0 < 640; k0 += 64) {
    __syncthreads();
    {
      const u16* src = A + (size_t)(bm0 + am) * 640 + k0 + ak0;
      *reinterpret_cast<short8*>(&As[am][ak0]) = *reinterpret_cast<const short8*>(src);
      *reinterpret_cast<short8*>(&As[am][ak0 + 8]) = *reinterpret_cast<const short8*>(src + 8);
    }
#pragma unroll
    for (int h = 0; h < 2; ++h) {
      int kk = k0 + bk + h * 32;
      short8 v = *reinterpret_cast<const short8*>(W + (size_t)kk * 64 + bn);
#pragma unroll
      for (int j = 0; j < 8; ++j) Bs[bn + j][bk + h * 32] = (u16)v[j];
    }
    __syncthreads();
    mfma_tile(As, Bs, wm, wn, lane, acc);
  }
#pragma unroll
  for (int r = 0; r < 2; ++r)
#pragma unroll
    for (int c = 0; c < 2; ++c)
#pragma unroll
      for (int i = 0; i < 4; ++i) {
        int col = wn + c * 16 + (lane & 15);
        sl[wm + r * 16 + ((lane >> 4) << 2) + i][col] = acc[r][c][i] + bias64[col];
      }
  __syncthreads();
  for (int task = tid; task < 64 * 32; task += 256) {
    int r = task >> 5, j = task & 31;
    size_t orow = (size_t)(bm0 + r);
    size_t base = orow * 1392 + 696;
    float mean = sl[r][j];
    float sd = 2.f * sigf(0.5f * sl[r][32 + j]) + 0.1f;
    float st = mean + sd * noise[orow * 32 + j];
    out[base + j] = mean;
    out[base + 32 + j] = sd;
    out[base + 64 + j] = st;
  }
}

// ---- the persistent scan: 6 independent producer/consumer pipelines --------
// A-blocks (90): parts[32-row half][128-col tile] = xd @ gruw
// BCD-blocks (12): LN+gates+deter + obs1 + obs2 + head + next-x for 16 rows
// flags[0..89]   = A progress   (A block h*15+c)
// flags[96..107] = BCD progress (BCD block b)
struct ScanArgs {
  u16* xd;            // [192][XDS] carry (sc1)
  float* parts;       // [192][1800] (sc1)
  const u16* gruwT;   // [1800][1216] (cached)
  const float* grub;
  const float* lns;
  const float* lnb;
  u16* dall;          // [12288][640] (nt; read after kernel end)
  float* out;
  const u16* o1wT;    // [640][640]
  const u16* epre;    // [64][192][600] (t-major, nt loads)
  const u16* o2wT;    // [64][640]
  const float* obs2b;
  const float* npo;
  const u16* w1pT;    // [640][64]
  const float* img1b;
  const float* action;
  unsigned* flags;
};

__global__ __launch_bounds__(512) void scan64(ScanArgs A) {
  const int bid = blockIdx.x, tid = threadIdx.x;
  const int lane = tid & 63, wave = tid >> 6;
  const int l15 = lane & 15;
  const int koff = (lane >> 4) << 3;   // k-octet offset within 32-k slab
  const int crow = (lane >> 4) << 2;   // C-row base within 16
  __shared__ __align__(16) char smem[144128];
  unsigned* flags = A.flags;

  if (bid < 90) {
    // ================= A block: h = 32-row half, c = 128-col tile =========
    u16 (*stg)[1224] = (u16(*)[1224])smem;  // 32 x 1224 bf16 = 78,336 B
    const int h = bid / 15, c = bid - h * 15;
    const int r0 = h * 32;
    const int fl = h * 15 + c;
    const int wrow = wave & 1, wcol = wave >> 1;
    const int c0 = c * 128 + wcol * 32 + l15, c1 = c0 + 16;
    const u16* b0p = A.gruwT + (size_t)(c0 < 1800 ? c0 : 0) * 1216 + koff;
    const u16* b1p = A.gruwT + (size_t)(c1 < 1800 ? c1 : 0) * 1216 + koff;

    for (int t = 0; t < 64; ++t) {
      if (tid == 0) {
        while ((int)min(ald32(&flags[96 + 2 * h]), ald32(&flags[97 + 2 * h])) < t)
          __builtin_amdgcn_s_sleep(2);
      }
      __syncthreads();
      // stage xd[r0..r0+31][0..1215] -> LDS (sc1, bulk, independent loads)
      for (int idx = tid; idx < 4864; idx += 512) {
        int r = idx / 152, ko = (idx - r * 152) * 8;
        *reinterpret_cast<short8*>(&stg[r][ko]) =
            ald16B(A.xd + (size_t)(r0 + r) * XDS + ko);
      }
      __syncthreads();
      {
        f32x4 acc0{}, acc1{};
#pragma unroll 2
        for (int kk = 0; kk < 1216; kk += 32) {
          short8 a = *reinterpret_cast<const short8*>(&stg[wrow * 16 + l15][koff + kk]);
          acc0 = MF(a, *reinterpret_cast<const short8*>(b0p + kk), acc0);
          acc1 = MF(a, *reinterpret_cast<const short8*>(b1p + kk), acc1);
        }
#pragma unroll
        for (int i = 0; i < 4; ++i) {
          float* pr = A.parts + (size_t)(r0 + wrow * 16 + crow + i) * 1800;
          if (c0 < 1800) astf(&pr[c0], acc0[i]);
          if (c1 < 1800) astf(&pr[c1], acc1[i]);
        }
      }
      __syncthreads();  // all waves' parts stores drained (vmcnt 0 at barrier)
      if (tid == 0) ast32(&flags[fl], (unsigned)(t + 1));
    }
  } else {
    // ================= BCD block: 16 rows R0..R0+15 =======================
    const int b = bid - 90, h = b >> 1;
    const int R0 = b * 16;
    float (*pl)[1800] = (float(*)[1800])smem;              // 57,600
    float (*dsh)[600] = (float(*)[600])(smem + 57600);     // 38,400
    u16 (*dl)[648] = (u16(*)[648])(smem + 96000);          // 20,736
    u16 (*hl)[648] = (u16(*)[648])(smem + 116736);         // 20,736
    float (*sl)[68] = (float(*)[68])(smem + 137472);       // 4,352
    u16 (*xa)[72] = (u16(*)[72])(smem + 141824);           // 2,304
    u16* es = (u16*)smem;                                  // epre stage (pl reuse)

    for (int idx = tid; idx < 16 * 648; idx += 512) {
      dl[idx / 648][idx % 648] = 0;
      hl[idx / 648][idx % 648] = 0;
    }
    for (int idx = tid; idx < 9600; idx += 512) dsh[idx / 600][idx % 600] = 0.f;

    for (int t = 0; t < 64; ++t) {
      {
        const unsigned tgt = (unsigned)(t + 1);
        if (tid < 64) {
          for (;;) {
            unsigned v = (lane < 15) ? ald32(&flags[h * 15 + lane]) : tgt;
            if (__all((int)(v >= tgt))) break;
            __builtin_amdgcn_s_sleep(2);
          }
        }
      }
      __syncthreads();
      // ---- LN + gates + deter update: wave w owns rows rb+w (two batches) --
      for (int rb = 0; rb < 16; rb += 8) {
        const int R16 = rb + wave;
        const float* prow = A.parts + (size_t)(R0 + R16) * 1800;
        float s = 0.f;
#pragma unroll
        for (int i = 0; i < 15; ++i) {
          int p = lane + 64 * i;
          if (p < 900) {
            unsigned long long u = ald64(prow + 2 * p);
            float vx = __uint_as_float((unsigned)u) + A.grub[2 * p];
            float vy = __uint_as_float((unsigned)(u >> 32)) + A.grub[2 * p + 1];
            pl[wave][2 * p] = vx;
            pl[wave][2 * p + 1] = vy;
            s += vx + vy;
          }
        }
#pragma unroll
        for (int o = 32; o; o >>= 1) s += __shfl_xor(s, o);
        float m = s * (1.f / 1800.f);
        float q = 0.f;
        for (int j = lane; j < 1800; j += 64) {
          float d = pl[wave][j] - m;
          q += d * d;
        }
#pragma unroll
        for (int o = 32; o; o >>= 1) q += __shfl_xor(q, o);
        float rstd = rsqrtf(q * (1.f / 1800.f) + 1e-5f);
        for (int j = lane; j < 600; j += 64) {
          float p0 = (pl[wave][j] - m) * rstd * A.lns[j] + A.lnb[j];
          float p1 = (pl[wave][600 + j] - m) * rstd * A.lns[600 + j] + A.lnb[600 + j];
          float p2 = (pl[wave][1200 + j] - m) * rstd * A.lns[1200 + j] + A.lnb[1200 + j];
          float r = sigf(p0);
          float cd = tanhf(r * p1);
          float u = sigf(p2 - 1.f);
          float dn = u * cd + (1.f - u) * dsh[R16][j];
          dsh[R16][j] = dn;
          dl[R16][j] = f2bf(dn);
        }
      }
      __syncthreads();
      // ---- deter outputs (xd sc1, out/dall nt) + epre stage ----------------
      for (int idx = tid; idx < 4800; idx += 512) {
        int r = idx / 300, jp = idx - r * 300, j = 2 * jp;
        float f0 = dsh[r][j], f1 = dsh[r][j + 1];
        unsigned pk = (unsigned)f2bf(f0) | ((unsigned)f2bf(f1) << 16);
        ast32(A.xd + (size_t)(R0 + r) * XDS + 600 + j, pk);
        size_t orow = (size_t)(R0 + r) * 64 + t;
        __builtin_nontemporal_store(pk, (unsigned*)(A.dall + orow * 640 + j));
        float* ob = A.out + orow * 1392;
        __builtin_nontemporal_store(f0, ob + 96 + j);
        __builtin_nontemporal_store(f1, ob + 97 + j);
        __builtin_nontemporal_store(f0, ob + 792 + j);
        __builtin_nontemporal_store(f1, ob + 793 + j);
      }
      if (tid < 320) {
        int r = tid / 20, qd = tid - r * 20;
        size_t orow = (size_t)(R0 + r) * 64 + t;
        __builtin_nontemporal_store(0u, (unsigned*)(A.dall + orow * 640 + 600 + 2 * qd));
      }
      for (int idx = tid; idx < 1200; idx += 512) {
        int r = idx / 75, ko = (idx - r * 75) * 8;
        short8 ev = __builtin_nontemporal_load(
            (short8*)(A.epre + ((size_t)t * 192 + R0 + r) * 600 + ko));
        *reinterpret_cast<short8*>(&es[r * 608 + ko]) = ev;
      }
      __syncthreads();
      // ---- obs1: hl = elu(deter @ obs1_w + epre)  (K-outer, acc[5]) -------
      {
        f32x4 acc[5] = {};
        const int cb = wave * 80;
        for (int kk = 0; kk < 640; kk += 32) {
          short8 a = *reinterpret_cast<const short8*>(&dl[l15][koff + kk]);
#pragma unroll
          for (int q = 0; q < 5; ++q) {
            const u16* bp = A.o1wT + (size_t)(cb + q * 16 + l15) * 640 + koff + kk;
            acc[q] = MF(a, *reinterpret_cast<const short8*>(bp), acc[q]);
          }
        }
#pragma unroll
        for (int q = 0; q < 5; ++q) {
          int cw = cb + q * 16 + l15;
          if (cw < 600) {
#pragma unroll
            for (int i = 0; i < 4; ++i) {
              int r = crow + i;
              hl[r][cw] = f2bf(eluf(acc[q][i] + bf2f(es[r * 608 + cw])));
            }
          }
        }
      }
      __syncthreads();
      // ---- obs2 (waves 0-3): sl = hl @ obs2_w + b -------------------------
      if (wave < 4) {
        const int n0 = wave * 16;
        const u16* bp = A.o2wT + (size_t)(n0 + l15) * 640 + koff;
        f32x4 acc{};
#pragma unroll 4
        for (int kk = 0; kk < 640; kk += 32)
          acc = MF(*reinterpret_cast<const short8*>(&hl[l15][koff + kk]),
                   *reinterpret_cast<const short8*>(bp + kk), acc);
#pragma unroll
        for (int i = 0; i < 4; ++i)
          sl[crow + i][n0 + l15] = acc[i] + A.obs2b[n0 + l15];
      }
      __syncthreads();
      // ---- head outputs + stoch + xa --------------------------------------
      {
        int r = tid >> 5, j = tid & 31;
        size_t orow = (size_t)(R0 + r) * 64 + t;
        float mean = sl[r][j];
        float sd = 2.f * sigf(0.5f * sl[r][32 + j]) + 0.1f;
        float st = mean + sd * __builtin_nontemporal_load((float*)&A.npo[orow * 32 + j]);
        float* ob = A.out + orow * 1392;
        __builtin_nontemporal_store(mean, ob + j);
        __builtin_nontemporal_store(sd, ob + 32 + j);
        __builtin_nontemporal_store(st, ob + 64 + j);
        xa[r][j] = f2bf(st);
      }
      if (tid < 256) {
        int r = tid >> 4, a2 = tid & 15;
        float av = (t < 63)
            ? __builtin_nontemporal_load(
                  (float*)&A.action[((size_t)(R0 + r) * 64 + t + 1) * 16 + a2])
            : 0.f;
        xa[r][32 + a2] = f2bf(av);
        xa[r][48 + a2] = 0;
      }
      __syncthreads();
      // ---- next x = elu([stoch, action] @ img1_w + b) -> xd (sc1) ---------
      if (t < 63) {
        for (int g = wave; g < 38; g += 8) {
          const u16* bp = A.w1pT + (size_t)(g * 16 + l15) * 64 + koff;
          f32x4 ax{};
          ax = MF(*reinterpret_cast<const short8*>(&xa[l15][koff]),
                  *reinterpret_cast<const short8*>(bp), ax);
          ax = MF(*reinterpret_cast<const short8*>(&xa[l15][32 + koff]),
                  *reinterpret_cast<const short8*>(bp + 32), ax);
          int cx = g * 16 + l15;
          if (cx < 600) {
            float bi = A.img1b[cx];
#pragma unroll
            for (int i = 0; i < 4; ++i) {
              unsigned hv = f2bf(eluf(ax[i] + bi));
              unsigned ov = (unsigned)__shfl_xor((int)hv, 1);
              if (!(lane & 1))
                ast32(A.xd + (size_t)(R0 + crow + i) * XDS + cx, hv | (ov << 16));
            }
          }
        }
      }
      __syncthreads();  // all waves' xd stores drained
      if (tid == 0) ast32(&flags[96 + b], (unsigned)(t + 1));
    }
  }
}

// ---------------- launch ----------------
extern "C" void kernel_launch(void* const* d_in, const int* in_sizes, int n_in,
                              void* d_out, int out_size, void* d_ws, size_t ws_size,
                              hipStream_t stream) {
  (void)in_sizes; (void)n_in; (void)out_size; (void)ws_size;
  const float* action = (const float*)d_in[0];
  const float* embed = (const float*)d_in[1];
  const float* npr = (const float*)d_in[2];
  const float* npo = (const float*)d_in[3];
  const float* img1w = (const float*)d_in[4];
  const float* img1b = (const float*)d_in[5];
  const float* gruw = (const float*)d_in[6];
  const float* grub = (const float*)d_in[7];
  const float* lns = (const float*)d_in[8];
  const float* lnb = (const float*)d_in[9];
  const float* img2w = (const float*)d_in[10];
  const float* img2b = (const float*)d_in[11];
  const float* img3w = (const float*)d_in[12];
  const float* img3b = (const float*)d_in[13];
  const float* obs1w = (const float*)d_in[14];
  const float* obs1b = (const float*)d_in[15];
  const float* obs2w = (const float*)d_in[16];
  const float* obs2b = (const float*)d_in[17];
  float* out = (float*)d_out;
  char* ws = (char*)d_ws;

  size_t off = 0;
  auto alloc = [&](size_t bytes) {
    size_t o = off;
    off += (bytes + 255) & ~(size_t)255;
    return o;
  };
  size_t o_bar = alloc(1024);
  size_t o_embed = alloc(12288ull * 1024 * 2);  // reused as dall (12288x640)
  size_t o_epre = alloc(12288ull * 600 * 2);    // reused (with o_wemb) as h_img
  size_t o_wemb = alloc(1024ull * 600 * 2);
  size_t o_gruwT = alloc(1800ull * 1216 * 2);
  size_t o_o1wT = alloc(640ull * 640 * 2);
  size_t o_o2wT = alloc(64ull * 640 * 2);
  size_t o_w1pT = alloc(640ull * 64 * 2);
  size_t o_i2w = alloc(640ull * 600 * 2);
  size_t o_i3w = alloc(640ull * 64 * 2);
  size_t o_xd = alloc(192ull * XDS * 2);
  size_t o_parts = alloc(192ull * 1800 * 4);

  unsigned* flags = (unsigned*)(ws + o_bar);
  u16* embed_bf = (u16*)(ws + o_embed);
  u16* dall = (u16*)(ws + o_embed);
  u16* epre = (u16*)(ws + o_epre);
  u16* himg = (u16*)(ws + o_epre);
  u16* wemb = (u16*)(ws + o_wemb);
  u16* gruwT = (u16*)(ws + o_gruwT);
  u16* o1wT = (u16*)(ws + o_o1wT);
  u16* o2wT = (u16*)(ws + o_o2wT);
  u16* w1pT = (u16*)(ws + o_w1pT);
  u16* i2wb = (u16*)(ws + o_i2w);
  u16* i3wb = (u16*)(ws + o_i3w);
  u16* xd = (u16*)(ws + o_xd);
  float* parts = (float*)(ws + o_parts);

  auto cgr = [](size_t total) {
    size_t g = (total + 255) / 256;
    return (unsigned)(g > 4096 ? 4096 : g);
  };

  // setup conversions
  conv_pad<<<cgr(12288ull * 1024), 256, 0, stream>>>(embed, embed_bf, 12288, 1024, 12288, 0);
  conv_pad<<<cgr(1024ull * 600), 256, 0, stream>>>(obs1w, wemb, 1024, 600, 1024, 600);
  conv_pad<<<cgr(640ull * 600), 256, 0, stream>>>(img2w, i2wb, 600, 600, 640, 0);
  conv_pad<<<cgr(640ull * 64), 256, 0, stream>>>(img3w, i3wb, 600, 64, 640, 0);
  conv_T<<<cgr(1800ull * 1216), 256, 0, stream>>>(gruw, gruwT, 1200, 1800, 1216, 1800);
  conv_T<<<cgr(640ull * 640), 256, 0, stream>>>(obs1w, o1wT, 600, 600, 640, 640);
  conv_T<<<cgr(64ull * 640), 256, 0, stream>>>(obs2w, o2wT, 600, 64, 640, 64);
  conv_T<<<cgr(640ull * 64), 256, 0, stream>>>(img1w, w1pT, 48, 600, 64, 640);

  k_init<<<192, 256, 0, stream>>>(action, img1w, img1b, xd, flags);

  // epre[t][b][600] = embed @ obs1_w[600:,:] + obs1_b   (bf16, t-major)
  gemm64<4><<<dim3(10, 192), 256, 0, stream>>>(embed_bf, 1024, wemb, 600, obs1b,
                                               epre, 600, 600, 600, 1024);

  // whole 64-step scan: 6 independent A->BCD pipelines, point-to-point flags
  ScanArgs sa;
  sa.xd = xd; sa.parts = parts;
  sa.gruwT = gruwT; sa.grub = grub; sa.lns = lns; sa.lnb = lnb;
  sa.dall = dall; sa.out = out;
  sa.o1wT = o1wT; sa.epre = epre;
  sa.o2wT = o2wT; sa.obs2b = obs2b; sa.npo = npo;
  sa.w1pT = w1pT; sa.img1b = img1b; sa.action = action;
  sa.flags = flags;
  scan64<<<NBLK, 512, 0, stream>>>(sa);

  // batched prior: h_img = elu(deter_all @ img2_w + img2_b), then img3 head
  gemm64<2><<<dim3(10, 192), 256, 0, stream>>>(dall, 640, i2wb, 600, img2b,
                                               himg, 640, 640, 600, 640);
  head_prior<<<192, 256, 0, stream>>>(himg, i3wb, img3b, npr, out);
}

// Round 9
// 4416.292 us; speedup vs baseline: 1.7951x; 1.1932x over previous
//
#include <hip/hip_runtime.h>

typedef unsigned short u16;
typedef __attribute__((ext_vector_type(8))) short short8;
typedef __attribute__((ext_vector_type(4))) float f32x4;

#define DEV __device__ __forceinline__

// B=192, T=64, ACT=16, EMB=1024, STOCH=32, DETER=600, HID=600
// out row stride 1392: [mean_po 0, std_po 32, stoch_po 64, deter 96,
//                       mean_pr 696, std_pr 728, stoch_pr 760, deter 792]
// xd row stride 1280: [x 0..599, deter 600..1199, zero pad 1200..1279]
#define XDS 1280
#define NBLK 60   // 48 A-blocks (6 row-halves x 8 XCD-pinned col-tiles) + 12 BD

DEV u16 f2bf(float f) {
  unsigned u = __float_as_uint(f);
  u = (u + 0x7FFFu + ((u >> 16) & 1u)) >> 16;
  return (u16)u;
}
DEV float bf2f(u16 h) { return __uint_as_float(((unsigned)h) << 16); }
DEV float sigf(float x) { return 1.f / (1.f + __expf(-x)); }
DEV float eluf(float x) { return x > 0.f ? x : __expf(x) - 1.f; }
DEV f32x4 MF(short8 a, short8 b, f32x4 c) {
  return __builtin_amdgcn_mfma_f32_16x16x32_bf16(a, b, c, 0, 0, 0);
}

// ---- agent-coherent (sc1, MALL-served) helpers: bypass L1/L2 so no fence /
// ---- L2 invalidate is needed; read-only weights stay warm in L2. ----
DEV unsigned long long ald64(const void* p) {
  return __hip_atomic_load((const unsigned long long*)p, __ATOMIC_RELAXED,
                           __HIP_MEMORY_SCOPE_AGENT);
}
DEV short8 ald16B(const u16* p) {
  union { unsigned long long u[2]; short8 v; } x;
  x.u[0] = ald64(p);
  x.u[1] = ald64(p + 4);
  return x.v;
}
DEV void ast32(void* p, unsigned v) {
  __hip_atomic_store((unsigned*)p, v, __ATOMIC_RELAXED, __HIP_MEMORY_SCOPE_AGENT);
}
DEV void astf(float* p, float v) { ast32(p, __float_as_uint(v)); }
DEV unsigned ald32(const unsigned* p) {
  return __hip_atomic_load(p, __ATOMIC_RELAXED, __HIP_MEMORY_SCOPE_AGENT);
}

// ---------------- f32 -> bf16 with zero row padding (k-major) ----------------
__global__ __launch_bounds__(256) void conv_pad(const float* __restrict__ src,
                                                u16* __restrict__ dst,
                                                int K, int N, int Kpad, int srcRowOff) {
  size_t total = (size_t)Kpad * N;
  for (size_t idx = (size_t)blockIdx.x * 256 + threadIdx.x; idx < total;
       idx += (size_t)gridDim.x * 256) {
    int k = (int)(idx / (size_t)N);
    int n = (int)(idx % (size_t)N);
    dst[idx] = (k < K) ? f2bf(src[(size_t)(k + srcRowOff) * N + n]) : (u16)0;
  }
}

// ---------------- f32 [K0][N0] -> bf16 transposed [Npad][Kpad] ----------------
__global__ __launch_bounds__(256) void conv_T(const float* __restrict__ src,
                                              u16* __restrict__ dst,
                                              int K0, int N0, int Kpad, int Npad) {
  size_t total = (size_t)Npad * Kpad;
  for (size_t idx = (size_t)blockIdx.x * 256 + threadIdx.x; idx < total;
       idx += (size_t)gridDim.x * 256) {
    int n = (int)(idx / (size_t)Kpad);
    int k = (int)(idx % (size_t)Kpad);
    dst[idx] = (k < K0 && n < N0) ? f2bf(src[(size_t)k * N0 + n]) : (u16)0;
  }
}

// ---------------- MFMA 64x64 tile core (LDS-staged, for setup/tail GEMMs) ----
DEV void mfma_tile(const u16 (*As)[72], const u16 (*Bs)[72], int wm, int wn,
                   int lane, f32x4 acc[2][2]) {
#pragma unroll
  for (int s = 0; s < 2; ++s) {
    const int ko = s * 32 + ((lane >> 4) << 3);
    short8 a0 = *reinterpret_cast<const short8*>(&As[wm + (lane & 15)][ko]);
    short8 a1 = *reinterpret_cast<const short8*>(&As[wm + 16 + (lane & 15)][ko]);
    short8 b0 = *reinterpret_cast<const short8*>(&Bs[wn + (lane & 15)][ko]);
    short8 b1 = *reinterpret_cast<const short8*>(&Bs[wn + 16 + (lane & 15)][ko]);
    acc[0][0] = MF(a0, b0, acc[0][0]);
    acc[0][1] = MF(a0, b1, acc[0][1]);
    acc[1][0] = MF(a1, b0, acc[1][0]);
    acc[1][1] = MF(a1, b1, acc[1][1]);
  }
}

// ---------------- generic 64x64-tiled bf16 GEMM (setup/tail) ----------------
// EPI: 2 = +bias, elu, bf16 out ; 4 = +bias, bf16 out, epre-permuted store
template <int EPI>
__global__ __launch_bounds__(256) void gemm64(
    const u16* __restrict__ A, int lda, const u16* __restrict__ W, int ldw,
    const float* __restrict__ bias, void* __restrict__ Cv, int ldc,
    int Nstore, int N, int K) {
  __shared__ u16 As[64][72];
  __shared__ u16 Bs[64][72];
  const int tid = threadIdx.x, lane = tid & 63, wave = tid >> 6;
  const int wm = (wave & 1) * 32, wn = (wave >> 1) * 32;
  const int bn0 = blockIdx.x * 64, bm0 = blockIdx.y * 64;
  const int am = tid >> 2, ak0 = (tid & 3) * 16;
  const int bk = tid >> 3, bn = (tid & 7) * 8;

  f32x4 acc[2][2] = {};
  for (int k0 = 0; k0 < K; k0 += 64) {
    __syncthreads();
    {
      const u16* src = A + (size_t)(bm0 + am) * lda + k0 + ak0;
      *reinterpret_cast<short8*>(&As[am][ak0]) = *reinterpret_cast<const short8*>(src);
      *reinterpret_cast<short8*>(&As[am][ak0 + 8]) = *reinterpret_cast<const short8*>(src + 8);
    }
    {
      int gn = bn0 + bn;
#pragma unroll
      for (int h = 0; h < 2; ++h) {
        int kk = k0 + bk + h * 32;
        short8 v;
        if (gn + 7 < N) {
          v = *reinterpret_cast<const short8*>(W + (size_t)kk * ldw + gn);
        } else {
          for (int j = 0; j < 8; ++j)
            v[j] = (gn + j < N) ? (short)W[(size_t)kk * ldw + gn + j] : (short)0;
        }
#pragma unroll
        for (int j = 0; j < 8; ++j) Bs[bn + j][bk + h * 32] = (u16)v[j];
      }
    }
    __syncthreads();
    mfma_tile(As, Bs, wm, wn, lane, acc);
  }

#pragma unroll
  for (int r = 0; r < 2; ++r)
#pragma unroll
    for (int c = 0; c < 2; ++c)
#pragma unroll
      for (int i = 0; i < 4; ++i) {
        int grow = bm0 + wm + r * 16 + ((lane >> 4) << 2) + i;
        int gcol = bn0 + wn + c * 16 + (lane & 15);
        if (gcol >= Nstore) continue;
        bool ok = gcol < N;
        float v = acc[r][c][i] + (ok ? bias[gcol] : 0.f);
        if (EPI == 2) {
          v = eluf(v);
          ((u16*)Cv)[(size_t)grow * ldc + gcol] = ok ? f2bf(v) : (u16)0;
        } else {  // EPI 4: epre[t][b][600] layout
          size_t row2 = (size_t)(grow & 63) * 192 + (size_t)(grow >> 6);
          ((u16*)Cv)[row2 * 600 + gcol] = f2bf(v);
        }
      }
}

// ------- init: x(t=0)=elu(action part), deter=0, pads=0, flags=0 ----------
__global__ __launch_bounds__(256) void k_init(const float* __restrict__ action,
                                              const float* __restrict__ img1w,
                                              const float* __restrict__ img1b,
                                              u16* __restrict__ xd,
                                              unsigned* __restrict__ flags) {
  __shared__ float act[16];
  int b = blockIdx.x, tid = threadIdx.x;
  if (b == 0 && tid < 128) flags[tid] = 0;  // kernel-end flush makes this visible
  if (tid < 16) act[tid] = action[(size_t)b * 64 * 16 + tid];  // t = 0
  __syncthreads();
  for (int h = tid; h < 600; h += 256) {
    float s = img1b[h];
#pragma unroll
    for (int a = 0; a < 16; ++a) s += act[a] * img1w[(size_t)(32 + a) * 600 + h];
    xd[(size_t)b * XDS + h] = f2bf(eluf(s));
  }
  for (int j = tid; j < 680; j += 256) xd[(size_t)b * XDS + 600 + j] = 0;
}

// ---------------- batched prior head (tail; N=64 GEMM + dist outputs) --------
__global__ __launch_bounds__(256) void head_prior(
    const u16* __restrict__ A, const u16* __restrict__ W,
    const float* __restrict__ bias64, const float* __restrict__ noise,
    float* __restrict__ out) {
  __shared__ u16 As[64][72];
  __shared__ u16 Bs[64][72];
  __shared__ float sl[64][68];
  const int tid = threadIdx.x, lane = tid & 63, wave = tid >> 6;
  const int wm = (wave & 1) * 32, wn = (wave >> 1) * 32;
  const int bm0 = blockIdx.x * 64;
  const int am = tid >> 2, ak0 = (tid & 3) * 16;
  const int bk = tid >> 3, bn = (tid & 7) * 8;

  f32x4 acc[2][2] = {};
  for (int k0 = 0; k0 < 640; k0 += 64) {
    __syncthreads();
    {
      const u16* src = A + (size_t)(bm0 + am) * 640 + k0 + ak0;
      *reinterpret_cast<short8*>(&As[am][ak0]) = *reinterpret_cast<const short8*>(src);
      *reinterpret_cast<short8*>(&As[am][ak0 + 8]) = *reinterpret_cast<const short8*>(src + 8);
    }
#pragma unroll
    for (int h = 0; h < 2; ++h) {
      int kk = k0 + bk + h * 32;
      short8 v = *reinterpret_cast<const short8*>(W + (size_t)kk * 64 + bn);
#pragma unroll
      for (int j = 0; j < 8; ++j) Bs[bn + j][bk + h * 32] = (u16)v[j];
    }
    __syncthreads();
    mfma_tile(As, Bs, wm, wn, lane, acc);
  }
#pragma unroll
  for (int r = 0; r < 2; ++r)
#pragma unroll
    for (int c = 0; c < 2; ++c)
#pragma unroll
      for (int i = 0; i < 4; ++i) {
        int col = wn + c * 16 + (lane & 15);
        sl[wm + r * 16 + ((lane >> 4) << 2) + i][col] = acc[r][c][i] + bias64[col];
      }
  __syncthreads();
  for (int task = tid; task < 64 * 32; task += 256) {
    int r = task >> 5, j = task & 31;
    size_t orow = (size_t)(bm0 + r);
    size_t base = orow * 1392 + 696;
    float mean = sl[r][j];
    float sd = 2.f * sigf(0.5f * sl[r][32 + j]) + 0.1f;
    float st = mean + sd * noise[orow * 32 + j];
    out[base + j] = mean;
    out[base + 32 + j] = sd;
    out[base + 64 + j] = st;
  }
}

// ---- the persistent scan: 6 pipelines of {8 A-blocks -> 2 BD-blocks} -------
// A-block (h,x): rows h*32..+31, col-groups g == x (mod 8) of 113 16-col groups.
//   x == bid&7 == XCD -> each XCD keeps ONE gruwT slice (~580 KB) L2-resident.
//   Split-K: deter half (K 608..1215) after BD's deter-flag, x half (K 0..607)
//   after BD's x-flag -> deter GEMM overlaps BD's obs1/obs2/head/img1.
// BD-block b: LN+gates+deter, obs1, obs2, head, next-x for rows b*16..+15.
// flags[0..47] A parts-progress (h*8+x); flags[96..107] BD x-flag;
// flags[112..123] BD deter-flag.
struct ScanArgs {
  u16* xd;            // [192][XDS] carry (sc1)
  float* parts;       // [192][1800] (sc1)
  const u16* gruwT;   // [1808][1216] (cached, cols 1800..1807 zero)
  const float* grub;
  const float* lns;
  const float* lnb;
  u16* dall;          // [12288][640] (nt; read after kernel end)
  float* out;
  const u16* o1wT;    // [640][640]
  const u16* epre;    // [64][192][600] (t-major, nt loads)
  const u16* o2wT;    // [64][640]
  const float* obs2b;
  const float* npo;
  const u16* w1pT;    // [640][64]
  const float* img1b;
  const float* action;
  unsigned* flags;
};

__global__ __launch_bounds__(512) void scan64(ScanArgs A) {
  const int bid = blockIdx.x, tid = threadIdx.x;
  const int lane = tid & 63, wave = tid >> 6;
  const int l15 = lane & 15;
  const int koff = (lane >> 4) << 3;   // k-octet offset within 32-k slab
  const int crow = (lane >> 4) << 2;   // C-row base within 16
  __shared__ __align__(16) char smem[144128];
  unsigned* flags = A.flags;

  if (bid < 48) {
    // ================= A block: h = 32-row half, x = XCD col-comb ==========
    u16 (*stg)[1224] = (u16(*)[1224])smem;  // 32 x 1224 bf16 = 78,336 B
    const int h = bid >> 3, x = bid & 7;
    const int r0 = h * 32;
    const int fl = h * 8 + x;
    const int J = (x == 0) ? 15 : 14;       // groups g = x + 8j, g <= 112
    const int g0 = x + 8 * wave;            // always valid (g0 <= 63)
    const int j1 = wave + 8;
    const bool has1 = (j1 < J);
    const int g1 = x + 8 * (has1 ? j1 : 0);
    const u16* bp0 = A.gruwT + (size_t)(16 * g0 + l15) * 1216 + koff;
    const u16* bp1 = A.gruwT + (size_t)(16 * g1 + l15) * 1216 + koff;

    for (int t = 0; t < 64; ++t) {
      f32x4 p00{}, p01{}, p10{}, p11{};
      // ---- A1: deter K-half (cols 608..1215); deter(t-1) ready when
      // ---- deter-flag >= t (set by BD iter t-1). t=0 trivially true. ----
      if (tid == 0) {
        while ((int)min(ald32(&flags[112 + 2 * h]), ald32(&flags[113 + 2 * h])) < t)
          __builtin_amdgcn_s_sleep(1);
      }
      __syncthreads();
      for (int idx = tid; idx < 2432; idx += 512) {  // 32 rows x octets 76..151
        int r = idx / 76, o = idx - r * 76 + 76;
        *reinterpret_cast<short8*>(&stg[r][o * 8]) =
            ald16B(A.xd + (size_t)(r0 + r) * XDS + o * 8);
      }
      __syncthreads();
      for (int kk = 608; kk < 1216; kk += 32) {
        short8 a0 = *reinterpret_cast<const short8*>(&stg[l15][koff + kk]);
        short8 a1 = *reinterpret_cast<const short8*>(&stg[16 + l15][koff + kk]);
        short8 b0 = *reinterpret_cast<const short8*>(bp0 + kk);
        p00 = MF(a0, b0, p00);
        p01 = MF(a1, b0, p01);
        if (has1) {
          short8 b1 = *reinterpret_cast<const short8*>(bp1 + kk);
          p10 = MF(a0, b1, p10);
          p11 = MF(a1, b1, p11);
        }
      }
      // ---- A2: x K-half (cols 0..607); x(t) ready when x-flag >= t ----
      if (tid == 0) {
        while ((int)min(ald32(&flags[96 + 2 * h]), ald32(&flags[97 + 2 * h])) < t)
          __builtin_amdgcn_s_sleep(1);
      }
      __syncthreads();
      for (int idx = tid; idx < 2432; idx += 512) {  // octets 0..75
        int r = idx / 76, o = idx - r * 76;
        *reinterpret_cast<short8*>(&stg[r][o * 8]) =
            ald16B(A.xd + (size_t)(r0 + r) * XDS + o * 8);
      }
      __syncthreads();
      for (int kk = 0; kk < 608; kk += 32) {
        short8 a0 = *reinterpret_cast<const short8*>(&stg[l15][koff + kk]);
        short8 a1 = *reinterpret_cast<const short8*>(&stg[16 + l15][koff + kk]);
        short8 b0 = *reinterpret_cast<const short8*>(bp0 + kk);
        p00 = MF(a0, b0, p00);
        p01 = MF(a1, b0, p01);
        if (has1) {
          short8 b1 = *reinterpret_cast<const short8*>(bp1 + kk);
          p10 = MF(a0, b1, p10);
          p11 = MF(a1, b1, p11);
        }
      }
      // ---- store parts (sc1) ----
      {
        const int c0 = 16 * g0 + l15;  // < 1800 always
#pragma unroll
        for (int i = 0; i < 4; ++i) {
          astf(A.parts + (size_t)(r0 + crow + i) * 1800 + c0, p00[i]);
          astf(A.parts + (size_t)(r0 + 16 + crow + i) * 1800 + c0, p01[i]);
        }
        if (has1) {
          const int c1 = 16 * g1 + l15;
          if (c1 < 1800) {
#pragma unroll
            for (int i = 0; i < 4; ++i) {
              astf(A.parts + (size_t)(r0 + crow + i) * 1800 + c1, p10[i]);
              astf(A.parts + (size_t)(r0 + 16 + crow + i) * 1800 + c1, p11[i]);
            }
          }
        }
      }
      __syncthreads();  // all waves' parts stores drained (vmcnt 0 at barrier)
      if (tid == 0) ast32(&flags[fl], (unsigned)(t + 1));
    }
  } else {
    // ================= BD block: 16 rows R0..R0+15 =======================
    const int b = bid - 48, h = b >> 1;
    const int R0 = b * 16;
    float (*pl)[1800] = (float(*)[1800])smem;              // 57,600
    float (*dsh)[600] = (float(*)[600])(smem + 57600);     // 38,400
    u16 (*dl)[648] = (u16(*)[648])(smem + 96000);          // 20,736
    u16 (*hl)[648] = (u16(*)[648])(smem + 116736);         // 20,736
    float (*sl)[68] = (float(*)[68])(smem + 137472);       // 4,352
    u16 (*xa)[72] = (u16(*)[72])(smem + 141824);           // 2,304
    u16* es = (u16*)smem;                                  // epre stage (pl reuse)

    for (int idx = tid; idx < 16 * 648; idx += 512) {
      dl[idx / 648][idx % 648] = 0;
      hl[idx / 648][idx % 648] = 0;
    }
    for (int idx = tid; idx < 9600; idx += 512) dsh[idx / 600][idx % 600] = 0.f;

    for (int t = 0; t < 64; ++t) {
      {
        const unsigned tgt = (unsigned)(t + 1);
        if (tid < 64) {
          for (;;) {
            unsigned v = (lane < 8) ? ald32(&flags[h * 8 + lane]) : tgt;
            if (__all((int)(v >= tgt))) break;
            __builtin_amdgcn_s_sleep(1);
          }
        }
      }
      __syncthreads();
      // ---- LN + gates + deter update: wave w owns rows rb+w (two batches) --
      for (int rb = 0; rb < 16; rb += 8) {
        const int R16 = rb + wave;
        const float* prow = A.parts + (size_t)(R0 + R16) * 1800;
        float s = 0.f;
#pragma unroll
        for (int i = 0; i < 15; ++i) {
          int p = lane + 64 * i;
          if (p < 900) {
            unsigned long long u = ald64(prow + 2 * p);
            float vx = __uint_as_float((unsigned)u) + A.grub[2 * p];
            float vy = __uint_as_float((unsigned)(u >> 32)) + A.grub[2 * p + 1];
            pl[wave][2 * p] = vx;
            pl[wave][2 * p + 1] = vy;
            s += vx + vy;
          }
        }
#pragma unroll
        for (int o = 32; o; o >>= 1) s += __shfl_xor(s, o);
        float m = s * (1.f / 1800.f);
        float q = 0.f;
        for (int j = lane; j < 1800; j += 64) {
          float d = pl[wave][j] - m;
          q += d * d;
        }
#pragma unroll
        for (int o = 32; o; o >>= 1) q += __shfl_xor(q, o);
        float rstd = rsqrtf(q * (1.f / 1800.f) + 1e-5f);
        for (int j = lane; j < 600; j += 64) {
          float p0 = (pl[wave][j] - m) * rstd * A.lns[j] + A.lnb[j];
          float p1 = (pl[wave][600 + j] - m) * rstd * A.lns[600 + j] + A.lnb[600 + j];
          float p2 = (pl[wave][1200 + j] - m) * rstd * A.lns[1200 + j] + A.lnb[1200 + j];
          float r = sigf(p0);
          float cd = tanhf(r * p1);
          float u = sigf(p2 - 1.f);
          float dn = u * cd + (1.f - u) * dsh[R16][j];
          dsh[R16][j] = dn;
          dl[R16][j] = f2bf(dn);
        }
      }
      __syncthreads();
      // ---- deter outputs (xd sc1, out/dall nt) ----------------------------
      for (int idx = tid; idx < 4800; idx += 512) {
        int r = idx / 300, jp = idx - r * 300, j = 2 * jp;
        float f0 = dsh[r][j], f1 = dsh[r][j + 1];
        unsigned pk = (unsigned)f2bf(f0) | ((unsigned)f2bf(f1) << 16);
        ast32(A.xd + (size_t)(R0 + r) * XDS + 600 + j, pk);
        size_t orow = (size_t)(R0 + r) * 64 + t;
        __builtin_nontemporal_store(pk, (unsigned*)(A.dall + orow * 640 + j));
        float* ob = A.out + orow * 1392;
        __builtin_nontemporal_store(f0, ob + 96 + j);
        __builtin_nontemporal_store(f1, ob + 97 + j);
        __builtin_nontemporal_store(f0, ob + 792 + j);
        __builtin_nontemporal_store(f1, ob + 793 + j);
      }
      if (tid < 320) {
        int r = tid / 20, qd = tid - r * 20;
        size_t orow = (size_t)(R0 + r) * 64 + t;
        __builtin_nontemporal_store(0u, (unsigned*)(A.dall + orow * 640 + 600 + 2 * qd));
      }
      __syncthreads();  // deter xd stores drained -> publish deter early
      if (tid == 0) ast32(&flags[112 + b], (unsigned)(t + 1));
      // ---- epre stage (nt loads) ------------------------------------------
      for (int idx = tid; idx < 1200; idx += 512) {
        int r = idx / 75, ko = (idx - r * 75) * 8;
        short8 ev = __builtin_nontemporal_load(
            (short8*)(A.epre + ((size_t)t * 192 + R0 + r) * 600 + ko));
        *reinterpret_cast<short8*>(&es[r * 608 + ko]) = ev;
      }
      __syncthreads();
      // ---- obs1: hl = elu(deter @ obs1_w + epre)  (K-outer, acc[5]) -------
      {
        f32x4 acc[5] = {};
        const int cb = wave * 80;
        for (int kk = 0; kk < 640; kk += 32) {
          short8 a = *reinterpret_cast<const short8*>(&dl[l15][koff + kk]);
#pragma unroll
          for (int q = 0; q < 5; ++q) {
            const u16* bp = A.o1wT + (size_t)(cb + q * 16 + l15) * 640 + koff + kk;
            acc[q] = MF(a, *reinterpret_cast<const short8*>(bp), acc[q]);
          }
        }
#pragma unroll
        for (int q = 0; q < 5; ++q) {
          int cw = cb + q * 16 + l15;
          if (cw < 600) {
#pragma unroll
            for (int i = 0; i < 4; ++i) {
              int r = crow + i;
              hl[r][cw] = f2bf(eluf(acc[q][i] + bf2f(es[r * 608 + cw])));
            }
          }
        }
      }
      __syncthreads();
      // ---- obs2 (waves 0-3): sl = hl @ obs2_w + b -------------------------
      if (wave < 4) {
        const int n0 = wave * 16;
        const u16* bp = A.o2wT + (size_t)(n0 + l15) * 640 + koff;
        f32x4 acc{};
#pragma unroll 4
        for (int kk = 0; kk < 640; kk += 32)
          acc = MF(*reinterpret_cast<const short8*>(&hl[l15][koff + kk]),
                   *reinterpret_cast<const short8*>(bp + kk), acc);
#pragma unroll
        for (int i = 0; i < 4; ++i)
          sl[crow + i][n0 + l15] = acc[i] + A.obs2b[n0 + l15];
      }
      __syncthreads();
      // ---- head outputs + stoch + xa --------------------------------------
      {
        int r = tid >> 5, j = tid & 31;
        size_t orow = (size_t)(R0 + r) * 64 + t;
        float mean = sl[r][j];
        float sd = 2.f * sigf(0.5f * sl[r][32 + j]) + 0.1f;
        float st = mean + sd * __builtin_nontemporal_load((float*)&A.npo[orow * 32 + j]);
        float* ob = A.out + orow * 1392;
        __builtin_nontemporal_store(mean, ob + j);
        __builtin_nontemporal_store(sd, ob + 32 + j);
        __builtin_nontemporal_store(st, ob + 64 + j);
        xa[r][j] = f2bf(st);
      }
      if (tid < 256) {
        int r = tid >> 4, a2 = tid & 15;
        float av = (t < 63)
            ? __builtin_nontemporal_load(
                  (float*)&A.action[((size_t)(R0 + r) * 64 + t + 1) * 16 + a2])
            : 0.f;
        xa[r][32 + a2] = f2bf(av);
        xa[r][48 + a2] = 0;
      }
      __syncthreads();
      // ---- next x = elu([stoch, action] @ img1_w + b) -> xd (sc1) ---------
      if (t < 63) {
        for (int g = wave; g < 38; g += 8) {
          const u16* bp = A.w1pT + (size_t)(g * 16 + l15) * 64 + koff;
          f32x4 ax{};
          ax = MF(*reinterpret_cast<const short8*>(&xa[l15][koff]),
                  *reinterpret_cast<const short8*>(bp), ax);
          ax = MF(*reinterpret_cast<const short8*>(&xa[l15][32 + koff]),
                  *reinterpret_cast<const short8*>(bp + 32), ax);
          int cx = g * 16 + l15;
          if (cx < 600) {
            float bi = A.img1b[cx];
#pragma unroll
            for (int i = 0; i < 4; ++i) {
              unsigned hv = f2bf(eluf(ax[i] + bi));
              unsigned ov = (unsigned)__shfl_xor((int)hv, 1);
              if (!(lane & 1))
                ast32(A.xd + (size_t)(R0 + crow + i) * XDS + cx, hv | (ov << 16));
            }
          }
        }
      }
      __syncthreads();  // all waves' xd stores drained
      if (tid == 0) ast32(&flags[96 + b], (unsigned)(t + 1));
    }
  }
}

// ---------------- launch ----------------
extern "C" void kernel_launch(void* const* d_in, const int* in_sizes, int n_in,
                              void* d_out, int out_size, void* d_ws, size_t ws_size,
                              hipStream_t stream) {
  (void)in_sizes; (void)n_in; (void)out_size; (void)ws_size;
  const float* action = (const float*)d_in[0];
  const float* embed = (const float*)d_in[1];
  const float* npr = (const float*)d_in[2];
  const float* npo = (const float*)d_in[3];
  const float* img1w = (const float*)d_in[4];
  const float* img1b = (const float*)d_in[5];
  const float* gruw = (const float*)d_in[6];
  const float* grub = (const float*)d_in[7];
  const float* lns = (const float*)d_in[8];
  const float* lnb = (const float*)d_in[9];
  const float* img2w = (const float*)d_in[10];
  const float* img2b = (const float*)d_in[11];
  const float* img3w = (const float*)d_in[12];
  const float* img3b = (const float*)d_in[13];
  const float* obs1w = (const float*)d_in[14];
  const float* obs1b = (const float*)d_in[15];
  const float* obs2w = (const float*)d_in[16];
  const float* obs2b = (const float*)d_in[17];
  float* out = (float*)d_out;
  char* ws = (char*)d_ws;

  size_t off = 0;
  auto alloc = [&](size_t bytes) {
    size_t o = off;
    off += (bytes + 255) & ~(size_t)255;
    return o;
  };
  size_t o_bar = alloc(1024);
  size_t o_embed = alloc(12288ull * 1024 * 2);  // reused as dall (12288x640)
  size_t o_epre = alloc(12288ull * 600 * 2);    // reused (with o_wemb) as h_img
  size_t o_wemb = alloc(1024ull * 600 * 2);
  size_t o_gruwT = alloc(1808ull * 1216 * 2);
  size_t o_o1wT = alloc(640ull * 640 * 2);
  size_t o_o2wT = alloc(64ull * 640 * 2);
  size_t o_w1pT = alloc(640ull * 64 * 2);
  size_t o_i2w = alloc(640ull * 600 * 2);
  size_t o_i3w = alloc(640ull * 64 * 2);
  size_t o_xd = alloc(192ull * XDS * 2);
  size_t o_parts = alloc(192ull * 1800 * 4);

  unsigned* flags = (unsigned*)(ws + o_bar);
  u16* embed_bf = (u16*)(ws + o_embed);
  u16* dall = (u16*)(ws + o_embed);
  u16* epre = (u16*)(ws + o_epre);
  u16* himg = (u16*)(ws + o_epre);
  u16* wemb = (u16*)(ws + o_wemb);
  u16* gruwT = (u16*)(ws + o_gruwT);
  u16* o1wT = (u16*)(ws + o_o1wT);
  u16* o2wT = (u16*)(ws + o_o2wT);
  u16* w1pT = (u16*)(ws + o_w1pT);
  u16* i2wb = (u16*)(ws + o_i2w);
  u16* i3wb = (u16*)(ws + o_i3w);
  u16* xd = (u16*)(ws + o_xd);
  float* parts = (float*)(ws + o_parts);

  auto cgr = [](size_t total) {
    size_t g = (total + 255) / 256;
    return (unsigned)(g > 4096 ? 4096 : g);
  };

  // setup conversions
  conv_pad<<<cgr(12288ull * 1024), 256, 0, stream>>>(embed, embed_bf, 12288, 1024, 12288, 0);
  conv_pad<<<cgr(1024ull * 600), 256, 0, stream>>>(obs1w, wemb, 1024, 600, 1024, 600);
  conv_pad<<<cgr(640ull * 600), 256, 0, stream>>>(img2w, i2wb, 600, 600, 640, 0);
  conv_pad<<<cgr(640ull * 64), 256, 0, stream>>>(img3w, i3wb, 600, 64, 640, 0);
  conv_T<<<cgr(1808ull * 1216), 256, 0, stream>>>(gruw, gruwT, 1200, 1800, 1216, 1808);
  conv_T<<<cgr(640ull * 640), 256, 0, stream>>>(obs1w, o1wT, 600, 600, 640, 640);
  conv_T<<<cgr(64ull * 640), 256, 0, stream>>>(obs2w, o2wT, 600, 64, 640, 64);
  conv_T<<<cgr(640ull * 64), 256, 0, stream>>>(img1w, w1pT, 48, 600, 64, 640);

  k_init<<<192, 256, 0, stream>>>(action, img1w, img1b, xd, flags);

  // epre[t][b][600] = embed @ obs1_w[600:,:] + obs1_b   (bf16, t-major)
  gemm64<4><<<dim3(10, 192), 256, 0, stream>>>(embed_bf, 1024, wemb, 600, obs1b,
                                               epre, 600, 600, 600, 1024);

  // whole 64-step scan: 6 {A x8 -> BD x2} pipelines, point-to-point flags
  ScanArgs sa;
  sa.xd = xd; sa.parts = parts;
  sa.gruwT = gruwT; sa.grub = grub; sa.lns = lns; sa.lnb = lnb;
  sa.dall = dall; sa.out = out;
  sa.o1wT = o1wT; sa.epre = epre;
  sa.o2wT = o2wT; sa.obs2b = obs2b; sa.npo = npo;
  sa.w1pT = w1pT; sa.img1b = img1b; sa.action = action;
  sa.flags = flags;
  scan64<<<NBLK, 512, 0, stream>>>(sa);

  // batched prior: h_img = elu(deter_all @ img2_w + img2_b), then img3 head
  gemm64<2><<<dim3(10, 192), 256, 0, stream>>>(dall, 640, i2wb, 600, img2b,
                                               himg, 640, 640, 600, 640);
  head_prior<<<192, 256, 0, stream>>>(himg, i3wb, img3b, npr, out);
}